// Round 4
// baseline (94.633 us; speedup 1.0000x reference)
//
#include <hip/hip_runtime.h>

#define T_LEN 32768
#define TT 128
#define SWZ(row) ((((row) >> 1) & 7) << 4)

typedef unsigned short ushort;
typedef unsigned int uint;
typedef __attribute__((ext_vector_type(8))) short short8;   // 8 bf16 (4 VGPRs)
typedef __attribute__((ext_vector_type(4))) float f32x4;
typedef __attribute__((ext_vector_type(2))) uint uint2v;

// Fragment-packed bf16 weights (written by pack_weights every launch — deterministic).
__device__ __align__(16) ushort g_packA1[9 * 8 * 64 * 8];   // conv(3 taps)+cond, 9 k-steps x 8 M-frags
__device__ __align__(16) ushort g_packA2[2 * 4 * 64 * 8];   // wout, 2 k-steps x 4 M-frags

static __device__ __forceinline__ ushort f2bf(float f) {    // RNE f32->bf16
    uint u = __float_as_uint(f);
    u += 0x7fffu + ((u >> 16) & 1u);
    return (ushort)(u >> 16);
}

// A-fragment layout for mfma_f32_16x16x32_bf16: lane l holds A[16m + (l&15)][32s + (l>>4)*8 + j]
__global__ void pack_weights(const float* __restrict__ wconv,
                             const float* __restrict__ wcond,
                             const float* __restrict__ wout) {
    int idx = blockIdx.x * 256 + threadIdx.x;
    if (idx < 9 * 8 * 64 * 8) {
        int j = idx & 7, l = (idx >> 3) & 63, m = (idx >> 9) & 7, s = idx >> 12;
        int row = m * 16 + (l & 15);
        int k = s * 32 + ((l >> 4) << 3) + j;          // 0..287
        float v;
        if (k < 192) v = wconv[row * 192 + (k & 63) * 3 + (k >> 6)];   // tap = k/64, c = k%64
        else { int cc = k - 192; v = (cc < 80) ? wcond[row * 80 + cc] : 0.f; }
        g_packA1[idx] = f2bf(v);
    } else {
        int e = idx - 9 * 8 * 64 * 8;                   // 4096 elems
        int j = e & 7, l = (e >> 3) & 63, m = (e >> 9) & 3, s = e >> 11;
        int row = m * 16 + (l & 15);
        int k = s * 32 + ((l >> 4) << 3) + j;           // 0..63
        g_packA2[e] = f2bf(wout[row * 64 + k]);
    }
}

// Staging item: 8 channels (one octet) x 4 t (one quad).
// 8 batched dwordx4 loads (coalesced across lanes: lane->tq), 4 conflict-free ds_write_b128.
static __device__ __forceinline__ void stage_x_item(
    const float* __restrict__ x, char* xs, int b, int t0, int oct, int tq)
{
    int tl = tq * 4;
    int gt0 = t0 - 16 + tl;           // halo=16 = 4 quads -> guard is whole-quad
    f32x4 v[8];
    if (gt0 >= 0) {
        #pragma unroll
        for (int j = 0; j < 8; ++j)
            v[j] = *(const f32x4*)(x + (size_t)(b * 64 + oct * 8 + j) * T_LEN + gt0);
    } else {
        #pragma unroll
        for (int j = 0; j < 8; ++j) v[j] = (f32x4){0.f, 0.f, 0.f, 0.f};
    }
    #pragma unroll
    for (int r = 0; r < 4; ++r) {
        short8 p;
        #pragma unroll
        for (int j = 0; j < 8; ++j) p[j] = (short)f2bf(v[j][r]);
        *(short8*)(xs + (tl + r) * 128 + ((uint)(oct * 16) ^ SWZ(tl + r))) = p;
    }
}

static __device__ __forceinline__ void stage_c_item(
    const float* __restrict__ cond, char* cs, int b, int t0, int oct, int tq, bool zero)
{
    int tl = tq * 4;
    f32x4 v[8];
    if (!zero) {
        #pragma unroll
        for (int j = 0; j < 8; ++j)
            v[j] = *(const f32x4*)(cond + (size_t)(b * 80 + oct * 8 + j) * T_LEN + t0 + tl);
    } else {
        #pragma unroll
        for (int j = 0; j < 8; ++j) v[j] = (f32x4){0.f, 0.f, 0.f, 0.f};
    }
    #pragma unroll
    for (int r = 0; r < 4; ++r) {
        short8 p;
        #pragma unroll
        for (int j = 0; j < 8; ++j) p[j] = (short)f2bf(v[j][r]);
        *(short8*)(cs + (tl + r) * 256 + ((uint)(oct * 16) ^ SWZ(tl + r))) = p;
    }
}

// 8 waves as 2x4 (mw x nw). Wave computes rows {32mw..+32} U {64+32mw..+32} x cols {32nw..+32}.
// Gate pairs (r, r+64) live in the same lane/reg -> register-only gate.
__global__ __launch_bounds__(512, 6) void wavenet_mfma(
    const float* __restrict__ x, const float* __restrict__ cond,
    const float* __restrict__ bconv, const float* __restrict__ bout,
    float* __restrict__ out, float* __restrict__ skip)
{
    // xs: [144 t][64 c] bf16, 128B rows, XOR swizzle byte^=((t>>1)&7)<<4; zs overlays later.
    // cs: [128 t][128 cc slots] bf16 (cc<96 used, 80..95 zeroed), 256B rows, same swizzle.
    __shared__ __align__(16) char lds[18432 + 32768];
    char* xs = lds;
    char* cs = lds + 18432;

    const int b   = blockIdx.x >> 8;
    const int t0  = (blockIdx.x & 255) * TT;
    const int tid = threadIdx.x;

    // ---- stage: x items = oct(0..7) x tq(0..35) = 288; cond items = oct(0..11) x tq(0..31) = 384 ----
    if (tid < 288) stage_x_item(x, xs, b, t0, tid / 36, tid % 36);
    if (tid >= 128) {
        int it = tid - 128;
        int oct = it >> 5;
        stage_c_item(cond, cs, b, t0, oct, it & 31, oct >= 10);
    }
    __syncthreads();

    const int lane = tid & 63;
    const int wv = tid >> 6;
    const int mw = wv & 1, nw = wv >> 1;          // 2 x 4
    const int l4 = lane >> 4, l15 = lane & 15;

    // ---- phase A: y = Wconv(*)x + Wcond*c + bconv ----
    f32x4 accA[2][2], accG[2][2];
    #pragma unroll
    for (int i = 0; i < 2; ++i) {
        int rbase = mw * 32 + i * 16 + l4 * 4;
        #pragma unroll
        for (int j = 0; j < 4; ++j) {
            float ba = bconv[rbase + j];
            float bg = bconv[64 + rbase + j];
            #pragma unroll
            for (int ni = 0; ni < 2; ++ni) { accA[i][ni][j] = ba; accG[i][ni][j] = bg; }
        }
    }

    const short8* pA1 = (const short8*)g_packA1;
    #pragma unroll
    for (int s = 0; s < 9; ++s) {
        short8 B[2];
        #pragma unroll
        for (int ni = 0; ni < 2; ++ni) {
            int col = nw * 32 + ni * 16 + l15;
            if (s < 6) {   // conv tap s>>1, c-half s&1: B[k=c][n=t], tap shifts t by 8*tap
                int tl = col + (s >> 1) * 8;
                int bc = (s & 1) * 64 + l4 * 16;
                B[ni] = *(const short8*)(xs + tl * 128 + (bc ^ SWZ(tl)));
            } else {       // cond k-step
                int bc = (s - 6) * 64 + l4 * 16;
                B[ni] = *(const short8*)(cs + col * 256 + (bc ^ SWZ(col)));
            }
        }
        #pragma unroll
        for (int i = 0; i < 2; ++i) {
            short8 Aa = pA1[(s * 8 + mw * 2 + i) * 64 + lane];
            short8 Ag = pA1[(s * 8 + 4 + mw * 2 + i) * 64 + lane];
            #pragma unroll
            for (int ni = 0; ni < 2; ++ni) {
                accA[i][ni] = __builtin_amdgcn_mfma_f32_16x16x32_bf16(Aa, B[ni], accA[i][ni], 0, 0, 0);
                accG[i][ni] = __builtin_amdgcn_mfma_f32_16x16x32_bf16(Ag, B[ni], accG[i][ni], 0, 0, 0);
            }
        }
    }
    __syncthreads();   // all xs reads done -> safe to overlay zs

    // ---- gate (register-only) + skip store + z -> LDS (bf16, B-operand layout) ----
    char* zs = lds;    // [128 t][64 r] bf16, 128B rows, same swizzle on row=t
    #pragma unroll
    for (int i = 0; i < 2; ++i) {
        int rb = mw * 32 + i * 16 + l4 * 4;
        #pragma unroll
        for (int ni = 0; ni < 2; ++ni) {
            int col = nw * 32 + ni * 16 + l15;
            float z[4];
            #pragma unroll
            for (int j = 0; j < 4; ++j) {
                float a = accA[i][ni][j], g = accG[i][ni][j];
                float th = 1.f - 2.f * __builtin_amdgcn_rcpf(__expf(2.f * a) + 1.f);
                float sg = __builtin_amdgcn_rcpf(1.f + __expf(-g));
                z[j] = th * sg;
                skip[(size_t)(b * 64 + rb + j) * T_LEN + t0 + col] = z[j];
            }
            uint p0 = (uint)f2bf(z[0]) | ((uint)f2bf(z[1]) << 16);
            uint p1 = (uint)f2bf(z[2]) | ((uint)f2bf(z[3]) << 16);
            *(uint2v*)(zs + col * 128 + ((uint)(rb * 2) ^ SWZ(col))) = (uint2v){p0, p1};
        }
    }
    __syncthreads();

    // ---- phase B: out = Wout @ z + bout ----
    f32x4 accO[2][2];
    #pragma unroll
    for (int i = 0; i < 2; ++i) {
        int rbase = mw * 32 + i * 16 + l4 * 4;
        #pragma unroll
        for (int j = 0; j < 4; ++j) {
            float bo = bout[rbase + j];
            #pragma unroll
            for (int ni = 0; ni < 2; ++ni) accO[i][ni][j] = bo;
        }
    }
    const short8* pA2 = (const short8*)g_packA2;
    #pragma unroll
    for (int s = 0; s < 2; ++s) {
        short8 B[2];
        #pragma unroll
        for (int ni = 0; ni < 2; ++ni) {
            int col = nw * 32 + ni * 16 + l15;
            int bc = s * 64 + l4 * 16;
            B[ni] = *(const short8*)(zs + col * 128 + (bc ^ SWZ(col)));
        }
        #pragma unroll
        for (int i = 0; i < 2; ++i) {
            short8 Ao = pA2[(s * 4 + mw * 2 + i) * 64 + lane];
            #pragma unroll
            for (int ni = 0; ni < 2; ++ni)
                accO[i][ni] = __builtin_amdgcn_mfma_f32_16x16x32_bf16(Ao, B[ni], accO[i][ni], 0, 0, 0);
        }
    }
    #pragma unroll
    for (int i = 0; i < 2; ++i) {
        int rb = mw * 32 + i * 16 + l4 * 4;
        #pragma unroll
        for (int ni = 0; ni < 2; ++ni) {
            int col = nw * 32 + ni * 16 + l15;
            #pragma unroll
            for (int j = 0; j < 4; ++j)
                out[(size_t)(b * 64 + rb + j) * T_LEN + t0 + col] = accO[i][ni][j];
        }
    }
}

extern "C" void kernel_launch(void* const* d_in, const int* in_sizes, int n_in,
                              void* d_out, int out_size, void* d_ws, size_t ws_size,
                              hipStream_t stream) {
    const float* x     = (const float*)d_in[0];
    const float* cond  = (const float*)d_in[1];
    const float* wconv = (const float*)d_in[2];
    const float* bconv = (const float*)d_in[3];
    const float* wout  = (const float*)d_in[4];
    const float* bout  = (const float*)d_in[5];
    const float* wcond = (const float*)d_in[6];

    float* out  = (float*)d_out;
    float* skip = out + (size_t)8 * 64 * T_LEN;   // outputs concatenated in return order

    pack_weights<<<dim3(160), 256, 0, stream>>>(wconv, wcond, wout);
    wavenet_mfma<<<dim3(8 * (T_LEN / TT)), 512, 0, stream>>>(x, cond, bconv, bout, out, skip);
}